// Round 1
// baseline (43.042 us; speedup 1.0000x reference)
//
#include <hip/hip_runtime.h>

#define BATCH 8388608
#define KCLS 5
#define EPS 1e-8f

__global__ __launch_bounds__(256) void cll_kernel(const float* __restrict__ logits,
                                                  const int* __restrict__ labels,
                                                  float* __restrict__ out) {
    const int tid = blockIdx.x * blockDim.x + threadIdx.x;
    const int stride = gridDim.x * blockDim.x;
    const int nvec = BATCH / 4;

    float acc = 0.0f;
    for (int i = tid; i < nvec; i += stride) {
        float4 x4 = reinterpret_cast<const float4*>(logits)[i];
        int4   l4 = reinterpret_cast<const int4*>(labels)[i];
        float xs[4] = {x4.x, x4.y, x4.z, x4.w};
        int   ls[4] = {l4.x, l4.y, l4.z, l4.w};
#pragma unroll
        for (int j = 0; j < 4; ++j) {
            float x = xs[j];
            int   l = ls[j];
            // upper = (l == K-1) ? 1 : sigmoid(l - x)
            float e_up = __expf(x - (float)l);
            float up   = (l == (KCLS - 1)) ? 1.0f : 1.0f / (1.0f + e_up);
            // lower = (l == 0) ? 0 : sigmoid((l-1) - x)
            float e_lo = __expf(x - (float)(l - 1));
            float lo   = (l == 0) ? 0.0f : 1.0f / (1.0f + e_lo);
            float p = up - lo;
            acc -= __logf(p + EPS);
        }
    }

    // wave (64-lane) butterfly reduce
#pragma unroll
    for (int off = 32; off > 0; off >>= 1)
        acc += __shfl_down(acc, off, 64);

    __shared__ float sdata[4];
    const int lane = threadIdx.x & 63;
    const int wid  = threadIdx.x >> 6;
    if (lane == 0) sdata[wid] = acc;
    __syncthreads();
    if (threadIdx.x == 0) {
        float s = sdata[0] + sdata[1] + sdata[2] + sdata[3];
        atomicAdd(out, s * (1.0f / (float)BATCH));
    }
}

extern "C" void kernel_launch(void* const* d_in, const int* in_sizes, int n_in,
                              void* d_out, int out_size, void* d_ws, size_t ws_size,
                              hipStream_t stream) {
    const float* logits = (const float*)d_in[0];
    const int*   labels = (const int*)d_in[1];
    float* out = (float*)d_out;

    // d_out is poisoned once before timing and NOT re-poisoned between replays:
    // zero it ourselves every call (async memset is graph-capture-safe).
    hipMemsetAsync(out, 0, sizeof(float), stream);

    const int block = 256;
    const int grid  = 2048;  // grid-stride; ~524k threads, 16 elems/thread
    cll_kernel<<<grid, block, 0, stream>>>(logits, labels, out);
}

// Round 2
// 41.471 us; speedup vs baseline: 1.0379x; 1.0379x over previous
//
#include <hip/hip_runtime.h>

#define BATCH   8388608
#define EPS     1e-8f
#define BLOCK   256
#define GRID    2048
#define STRIDE  (GRID * BLOCK)          // 524288 threads
#define NVEC    (BATCH / 4)             // 2097152 vec4 groups
#define ITERS   (NVEC / STRIDE)         // exactly 4

__global__ __launch_bounds__(BLOCK) void cll_kernel(const float4* __restrict__ logits,
                                                    const int4* __restrict__ labels,
                                                    float* __restrict__ out) {
    const int tid = blockIdx.x * BLOCK + threadIdx.x;

    // Hoist ALL loads first: 8 independent VMEM ops in flight per thread.
    float4 x4[ITERS];
    int4   l4[ITERS];
#pragma unroll
    for (int k = 0; k < ITERS; ++k) {
        x4[k] = logits[tid + k * STRIDE];
        l4[k] = labels[tid + k * STRIDE];
    }

    float acc = 0.0f;
#pragma unroll
    for (int k = 0; k < ITERS; ++k) {
        const float xs[4] = {x4[k].x, x4[k].y, x4[k].z, x4[k].w};
        const int   ls[4] = {l4[k].x, l4[k].y, l4[k].z, l4[k].w};
#pragma unroll
        for (int j = 0; j < 4; ++j) {
            const float x = xs[j];
            const int   l = ls[j];
            // upper = (l==4) ? 1 : sigmoid(l - x);  lower = (l==0) ? 0 : sigmoid(l-1-x)
            // eu = exp(-(l-x)) = exp(x-l);  el = exp(x-(l-1)) = eu * e
            const float eu = __expf(x - (float)l);
            const float el = eu * 2.71828182845904523536f;
            const float Du = 1.0f + eu;
            const float Dl = 1.0f + el;
            // middle: p = (el-eu)/(Du*Dl);  l==0: p = 1/Du;  l==4: p = el/Dl
            const float N = (l == 0) ? 1.0f : ((l == 4) ? el : (el - eu));
            const float D = (l == 0) ? Du   : ((l == 4) ? Dl : Du * Dl);
            const float p = N * __builtin_amdgcn_rcpf(D);
            acc -= __logf(p + EPS);
        }
    }

    // wave (64-lane) butterfly reduce
#pragma unroll
    for (int off = 32; off > 0; off >>= 1)
        acc += __shfl_down(acc, off, 64);

    __shared__ float sdata[BLOCK / 64];
    const int lane = threadIdx.x & 63;
    const int wid  = threadIdx.x >> 6;
    if (lane == 0) sdata[wid] = acc;
    __syncthreads();
    if (threadIdx.x == 0) {
        float s = sdata[0] + sdata[1] + sdata[2] + sdata[3];
        atomicAdd(out, s * (1.0f / (float)BATCH));
    }
}

extern "C" void kernel_launch(void* const* d_in, const int* in_sizes, int n_in,
                              void* d_out, int out_size, void* d_ws, size_t ws_size,
                              hipStream_t stream) {
    const float4* logits = (const float4*)d_in[0];
    const int4*   labels = (const int4*)d_in[1];
    float* out = (float*)d_out;

    // d_out is poisoned once before timing and NOT re-poisoned between replays:
    // zero it ourselves every call (async memset is graph-capture-safe).
    hipMemsetAsync(out, 0, sizeof(float), stream);

    cll_kernel<<<GRID, BLOCK, 0, stream>>>(logits, labels, out);
}

// Round 3
// 19.214 us; speedup vs baseline: 2.2402x; 2.1585x over previous
//
#include <hip/hip_runtime.h>

#define BATCH   8388608
#define EPS     1e-8f
#define BLOCK   256
#define GRID    2048
#define STRIDE  (GRID * BLOCK)          // 524288 threads
#define NVEC    (BATCH / 4)             // 2097152 vec4 groups
#define ITERS   (NVEC / STRIDE)         // exactly 4

__global__ __launch_bounds__(BLOCK) void cll_main(const float4* __restrict__ logits,
                                                  const int4* __restrict__ labels,
                                                  float* __restrict__ partials) {
    const int tid = blockIdx.x * BLOCK + threadIdx.x;

    // Hoist ALL loads first: 8 independent VMEM ops in flight per thread (128 B).
    float4 x4[ITERS];
    int4   l4[ITERS];
#pragma unroll
    for (int k = 0; k < ITERS; ++k) {
        x4[k] = logits[tid + k * STRIDE];
        l4[k] = labels[tid + k * STRIDE];
    }

    float acc = 0.0f;
#pragma unroll
    for (int k = 0; k < ITERS; ++k) {
        const float xs[4] = {x4[k].x, x4[k].y, x4[k].z, x4[k].w};
        const int   ls[4] = {l4[k].x, l4[k].y, l4[k].z, l4[k].w};
#pragma unroll
        for (int j = 0; j < 4; ++j) {
            const float x = xs[j];
            const int   l = ls[j];
            // upper = (l==4) ? 1 : sigmoid(l - x);  lower = (l==0) ? 0 : sigmoid(l-1-x)
            // eu = exp(x-l);  el = exp(x-(l-1)) = eu * e
            const float eu = __expf(x - (float)l);
            const float el = eu * 2.71828182845904523536f;
            const float Du = 1.0f + eu;
            const float Dl = 1.0f + el;
            // middle: p = (el-eu)/(Du*Dl);  l==0: p = 1/Du;  l==4: p = el/Dl
            const float N = (l == 0) ? 1.0f : ((l == 4) ? el : (el - eu));
            const float D = (l == 0) ? Du   : ((l == 4) ? Dl : Du * Dl);
            const float p = N * __builtin_amdgcn_rcpf(D);
            acc -= __logf(p + EPS);
        }
    }

    // wave (64-lane) butterfly reduce
#pragma unroll
    for (int off = 32; off > 0; off >>= 1)
        acc += __shfl_down(acc, off, 64);

    __shared__ float sdata[BLOCK / 64];
    const int lane = threadIdx.x & 63;
    const int wid  = threadIdx.x >> 6;
    if (lane == 0) sdata[wid] = acc;
    __syncthreads();
    if (threadIdx.x == 0)
        partials[blockIdx.x] = sdata[0] + sdata[1] + sdata[2] + sdata[3];
}

// One block: reduce GRID partials -> d_out[0] (plain overwrite, no init needed).
__global__ __launch_bounds__(BLOCK) void cll_reduce(const float* __restrict__ partials,
                                                    float* __restrict__ out) {
    const float4* p4 = (const float4*)partials;   // GRID/4 = 512 float4
    float4 a = p4[threadIdx.x];                   // [0, 1024)
    float4 b = p4[threadIdx.x + BLOCK];           // [1024, 2048)
    float acc = (a.x + a.y) + (a.z + a.w) + (b.x + b.y) + (b.z + b.w);

#pragma unroll
    for (int off = 32; off > 0; off >>= 1)
        acc += __shfl_down(acc, off, 64);

    __shared__ float sdata[BLOCK / 64];
    const int lane = threadIdx.x & 63;
    const int wid  = threadIdx.x >> 6;
    if (lane == 0) sdata[wid] = acc;
    __syncthreads();
    if (threadIdx.x == 0) {
        float s = sdata[0] + sdata[1] + sdata[2] + sdata[3];
        out[0] = s * (1.0f / (float)BATCH);
    }
}

extern "C" void kernel_launch(void* const* d_in, const int* in_sizes, int n_in,
                              void* d_out, int out_size, void* d_ws, size_t ws_size,
                              hipStream_t stream) {
    const float4* logits = (const float4*)d_in[0];
    const int4*   labels = (const int4*)d_in[1];
    float* partials = (float*)d_ws;   // 2048 floats = 8 KB scratch
    float* out = (float*)d_out;

    cll_main<<<GRID, BLOCK, 0, stream>>>(logits, labels, partials);
    cll_reduce<<<1, BLOCK, 0, stream>>>(partials, out);
}